// Round 1
// baseline (561.312 us; speedup 1.0000x reference)
//
#include <hip/hip_runtime.h>

// Problem constants
#define B_   4
#define N_   1024
#define R_   5
#define DIM_ 1024
#define H_   16
#define DH_  64
#define NJ   1056          // padded key count: 1 null + 1024 + 31 pad (33 tiles of 32)
#define CDIM 320           // R_*DH_ effective head width
#define MROWS (B_*N_*R_)   // 20480

typedef unsigned int u32;
typedef unsigned short u16;
typedef __attribute__((ext_vector_type(8))) short bf16x8;
typedef __attribute__((ext_vector_type(4))) float f32x4;

constexpr float SCALE_ = (float)(0.125 * (1.0 / 128.0) * 0.4472135954999579); // DH^-.5 /ALPHA /sqrt(R)
constexpr float ALPHA_ = 128.0f;

__device__ __forceinline__ u16 f2bf(float f) {
  u32 u = __builtin_bit_cast(u32, f);
  u32 r = (u + 0x7fffu + ((u >> 16) & 1u)) >> 16;   // RNE
  return (u16)r;
}
__device__ __forceinline__ u32 pack2(float lo, float hi) {
  return (u32)f2bf(lo) | ((u32)f2bf(hi) << 16);
}
__device__ __forceinline__ void gld_lds16(void* lds, const void* g) {
  __builtin_amdgcn_global_load_lds((const __attribute__((address_space(1))) u32*)g,
                                   (__attribute__((address_space(3))) u32*)lds, 16, 0, 0);
}

// ---------------- mask dtype detection (bool may arrive as i8/i32/f32/i64) ----------------
__global__ void mask_detect(const u32* __restrict__ m, int* __restrict__ flag) {
  int t = threadIdx.x;
  int fl = 0;
  for (int i = t; i < 1024; i += 256) {     // 4KB scan: safe under every candidate encoding
    u32 wv = m[i];
    if (wv == 0x3f800000u) fl |= 4;         // float 1.0 present -> f32 mask
    else if (wv > 1u) fl |= 2;              // packed-byte patterns (e.g. 0x01010101)
    if ((i & 1) && wv == 1u) fl |= 1;       // odd word == 1 -> not i64 layout
  }
  if (fl) atomicOr(flag, fl);
}

__global__ void build_bias(const void* __restrict__ mask, const int* __restrict__ flag,
                           float* __restrict__ biasg) {
  int idx = blockIdx.x * 256 + threadIdx.x;
  if (idx >= B_ * NJ) return;
  int b = idx / NJ, j = idx % NJ;
  int mv;
  if (j == 0) mv = 1;                 // null token always attended
  else if (j > N_) mv = 0;            // pad
  else {
    int fb = flag[0];
    int mode = (fb & 4) ? 2 : ((fb & 2) ? 1 : ((fb & 1) ? 0 : 3));
    int mi = b * N_ + (j - 1);
    if (mode == 0)      mv = ((const int*)mask)[mi] != 0;
    else if (mode == 1) mv = ((const unsigned char*)mask)[mi] != 0;
    else if (mode == 2) mv = ((const float*)mask)[mi] != 0.0f;
    else                mv = ((const int*)mask)[mi * 2] != 0;   // i64 little-endian low word
  }
  biasg[idx] = mv ? 0.0f : -__builtin_inff();
}

// ---------------- null kv row + pad rows ----------------
__global__ void kvfill(const float* __restrict__ nullkv, u16* __restrict__ kg, u16* __restrict__ vTg) {
  int idx = blockIdx.x * 256 + threadIdx.x;
  if (idx >= B_ * 32 * CDIM) return;
  int c  = idx % CDIM;
  int jj = (idx / CDIM) & 31;
  int b  = idx / (CDIM * 32);
  int j  = (jj == 0) ? 0 : (1024 + jj);    // j=0 null row, j in [1025,1056) pad
  u16 kvv, vvv;
  if (jj == 0) { kvv = f2bf(nullkv[c & 63]); vvv = f2bf(nullkv[64 + (c & 63)]); }
  else         { kvv = 0; vvv = 0; }
  kg [(size_t)(b * NJ + j) * CDIM + c] = kvv;      // K row-major [B][NJ][320]
  vTg[(size_t)(b * CDIM + c) * NJ + j] = vvv;      // V transposed [B][320][NJ]
}

// ---------------- weight transpose + bf16 cast:  WT[n][k] = W[k][n] ----------------
__global__ __launch_bounds__(256) void transpose_cast(const float* __restrict__ W,
                                                      u16* __restrict__ WT, int K, int Nn) {
  __shared__ float tile[32][33];
  int tx = threadIdx.x & 31, ty = threadIdx.x >> 5;
  int n0 = blockIdx.x * 32, k0 = blockIdx.y * 32;
  #pragma unroll
  for (int e = 0; e < 4; ++e)
    tile[ty + e * 8][tx] = W[(size_t)(k0 + ty + e * 8) * Nn + n0 + tx];
  __syncthreads();
  #pragma unroll
  for (int e = 0; e < 4; ++e)
    WT[(size_t)(n0 + ty + e * 8) * K + k0 + tx] = f2bf(tile[tx][ty + e * 8]);
}

// ---------------- input LayerNorm -> xn(bf16), plus raw x cast -> xb(bf16) ----------------
__global__ __launch_bounds__(256) void ln_in(const float* __restrict__ x, const float* __restrict__ gin,
                                             u16* __restrict__ xn, u16* __restrict__ xb) {
  const size_t row = blockIdx.x;
  const int t = threadIdx.x, w = t >> 6, lane = t & 63;
  const float* xr = x + row * 1024;
  f32x4 v = *(const f32x4*)(xr + t * 4);
  float s = v[0] + v[1] + v[2] + v[3];
  #pragma unroll
  for (int o = 1; o < 64; o <<= 1) s += __shfl_xor(s, o);
  __shared__ float red[8];
  if (lane == 0) red[w] = s;
  __syncthreads();
  float mean = (red[0] + red[1] + red[2] + red[3]) * (1.0f / 1024.0f);
  f32x4 d;
  float ss = 0.f;
  #pragma unroll
  for (int e = 0; e < 4; ++e) { d[e] = v[e] - mean; ss += d[e] * d[e]; }
  #pragma unroll
  for (int o = 1; o < 64; o <<= 1) ss += __shfl_xor(ss, o);
  if (lane == 0) red[4 + w] = ss;
  __syncthreads();
  float var = (red[4] + red[5] + red[6] + red[7]) * (1.0f / 1024.0f);
  float rs = rsqrtf(var + 1e-5f);
  f32x4 gv = *(const f32x4*)(gin + t * 4);
  uint2 o1, o2;
  o1.x = pack2(d[0] * rs * gv[0], d[1] * rs * gv[1]);
  o1.y = pack2(d[2] * rs * gv[2], d[3] * rs * gv[3]);
  o2.x = pack2(v[0], v[1]);
  o2.y = pack2(v[2], v[3]);
  *(uint2*)(xn + row * 1024 + t * 4) = o1;
  *(uint2*)(xb + row * 1024 + t * 4) = o2;
}

// ---------------- output LayerNorm, in place on fp32 rows ----------------
__global__ __launch_bounds__(256) void ln_out(float* __restrict__ y, const float* __restrict__ gout) {
  const size_t row = blockIdx.x;
  const int t = threadIdx.x, w = t >> 6, lane = t & 63;
  float* yr = y + row * 1024;
  f32x4 v = *(const f32x4*)(yr + t * 4);
  float s = v[0] + v[1] + v[2] + v[3];
  #pragma unroll
  for (int o = 1; o < 64; o <<= 1) s += __shfl_xor(s, o);
  __shared__ float red[8];
  if (lane == 0) red[w] = s;
  __syncthreads();
  float mean = (red[0] + red[1] + red[2] + red[3]) * (1.0f / 1024.0f);
  f32x4 d;
  float ss = 0.f;
  #pragma unroll
  for (int e = 0; e < 4; ++e) { d[e] = v[e] - mean; ss += d[e] * d[e]; }
  #pragma unroll
  for (int o = 1; o < 64; o <<= 1) ss += __shfl_xor(ss, o);
  if (lane == 0) red[4 + w] = ss;
  __syncthreads();
  float var = (red[4] + red[5] + red[6] + red[7]) * (1.0f / 1024.0f);
  float rs = rsqrtf(var + 1e-5f);
  f32x4 gv = *(const f32x4*)(gout + t * 4);
  f32x4 o;
  #pragma unroll
  for (int e = 0; e < 4; ++e) o[e] = d[e] * rs * gv[e];
  *(f32x4*)(yr + t * 4) = o;
}

// ---------------- m97-style 128x128 BK=32 bf16 GEMM, B given transposed [N][K] ----------------
// EPI 0: C=bf16, *SCALE (q-proj).  EPI 1: kv scatter (K rowmajor / V transposed).  EPI 2: C=f32.
template <int EPI>
__global__ __launch_bounds__(256) void gemm_bt(const u16* __restrict__ A, const u16* __restrict__ BT,
                                               void* __restrict__ C0, void* __restrict__ C1,
                                               const int K, const int Nn) {
  __shared__ __align__(16) u16 As[128 * 32];
  __shared__ __align__(16) u16 Bs[128 * 32];
  const int t = threadIdx.x, w = t >> 6, lane = t & 63;
  const int g = lane >> 4, i16 = lane & 15;
  const int wr = w >> 1, wc = w & 1;
  const size_t m0 = (size_t)blockIdx.y * 128;
  const size_t n0 = (size_t)blockIdx.x * 128;
  const u16* Ab = A + m0 * K;
  const u16* Bb = BT + n0 * K;
  f32x4 acc[4][4];
  #pragma unroll
  for (int mi = 0; mi < 4; ++mi)
    #pragma unroll
    for (int ni = 0; ni < 4; ++ni) acc[mi][ni] = (f32x4){0.f, 0.f, 0.f, 0.f};

  for (int k0 = 0; k0 < K; k0 += 32) {
    __syncthreads();
    #pragma unroll
    for (int s = 0; s < 2; ++s) {
      int c = s * 256 + t;                      // 16B chunk id; row = c/4, col8 = (c&3)*8
      gld_lds16(&As[(s * 256 + w * 64) * 8], Ab + (size_t)(c >> 2) * K + k0 + (c & 3) * 8);
      gld_lds16(&Bs[(s * 256 + w * 64) * 8], Bb + (size_t)(c >> 2) * K + k0 + (c & 3) * 8);
    }
    __syncthreads();
    bf16x8 af[4], bfr[4];
    #pragma unroll
    for (int mi = 0; mi < 4; ++mi) af[mi]  = *(const bf16x8*)&As[(wr * 64 + mi * 16 + i16) * 32 + g * 8];
    #pragma unroll
    for (int ni = 0; ni < 4; ++ni) bfr[ni] = *(const bf16x8*)&Bs[(wc * 64 + ni * 16 + i16) * 32 + g * 8];
    #pragma unroll
    for (int mi = 0; mi < 4; ++mi)
      #pragma unroll
      for (int ni = 0; ni < 4; ++ni)
        acc[mi][ni] = __builtin_amdgcn_mfma_f32_16x16x32_bf16(af[mi], bfr[ni], acc[mi][ni], 0, 0, 0);
  }

  #pragma unroll
  for (int mi = 0; mi < 4; ++mi)
    #pragma unroll
    for (int ni = 0; ni < 4; ++ni)
      #pragma unroll
      for (int reg = 0; reg < 4; ++reg) {
        size_t gr = m0 + wr * 64 + mi * 16 + g * 4 + reg;
        int gc = (int)n0 + wc * 64 + ni * 16 + i16;
        float v = acc[mi][ni][reg];
        if (EPI == 0) {
          ((u16*)C0)[gr * 1024 + gc] = f2bf(v * SCALE_);
        } else if (EPI == 1) {
          int grr = (int)gr;
          int b = grr / (N_ * R_);
          int rem = grr - b * (N_ * R_);
          int n = rem / R_;
          int r = rem - n * R_;
          u16 val = f2bf(v);
          if (gc < DH_) ((u16*)C0)[(size_t)(b * NJ + n + 1) * CDIM + r * 64 + gc] = val;
          else          ((u16*)C1)[(size_t)(b * CDIM + r * 64 + (gc - DH_)) * NJ + (n + 1)] = val;
        } else {
          ((float*)C0)[gr * 1024 + gc] = v;
        }
      }
}

// ---------------- flash attention: 64 q-rows/block (4 waves x16), j-tiles of 32 ----------------
__global__ __launch_bounds__(256) void attn_kernel(const u16* __restrict__ qb, const u16* __restrict__ kg,
                                                   const u16* __restrict__ vTg, const float* __restrict__ biasg,
                                                   u16* __restrict__ attout) {
  const int blk = blockIdx.x;
  const int it = blk & 15;
  const int h  = (blk >> 4) & 15;
  const int b  = blk >> 8;
  const int t = threadIdx.x;
  const int w = t >> 6, lane = t & 63;
  const int g = lane >> 4, i16 = lane & 15;
  const int i0 = it * 64 + w * 16;

  __shared__ __align__(16) u16 Klds[32 * 328];    // [32 j][320 c] padded +8 -> <=2-way conflicts
  __shared__ __align__(16) u16 VTlds[320 * 40];   // [320 c][32 j] padded +8
  __shared__ __align__(16) float biaslds[32];

  // Q fragments (lane holds Q[i0+i16][k-slice]); serves as MFMA B-operand for S^T = K*Q^T
  bf16x8 qf[10];
  {
    const int gi = i0 + i16;
    const u16* qrow = qb + (size_t)((b * N_ + gi) * R_) * 1024 + h * 64;
    #pragma unroll
    for (int kk = 0; kk < 10; ++kk)
      qf[kk] = *(const bf16x8*)(qrow + (kk >> 1) * 1024 + (kk & 1) * 32 + g * 8);
  }

  f32x4 O[20];
  #pragma unroll
  for (int f = 0; f < 20; ++f) O[f] = (f32x4){0.f, 0.f, 0.f, 0.f};
  float m_run = -__builtin_inff(), d_run = 0.f;

  for (int jt = 0; jt < 33; ++jt) {
    const int j0 = jt * 32;
    __syncthreads();
    // stage K tile [32][320] and V^T tile [320][32]
    #pragma unroll
    for (int s = 0; s < 5; ++s) {
      int c = t + 256 * s;
      int row = c / 40, col8 = (c % 40) * 8;
      uint4 kv4 = *(const uint4*)(kg + (size_t)(b * NJ + j0 + row) * CDIM + col8);
      *(uint4*)&Klds[row * 328 + col8] = kv4;
      int vrow = c >> 2, j8 = (c & 3) * 8;
      uint4 vv4 = *(const uint4*)(vTg + (size_t)(b * CDIM + vrow) * NJ + j0 + j8);
      *(uint4*)&VTlds[vrow * 40 + j8] = vv4;
    }
    if (t < 32) biaslds[t] = biasg[b * NJ + j0 + t];
    __syncthreads();

    // S^T tiles: rows j (2 frags of 16), cols i. A = K rows, B = Q.
    f32x4 s0 = (f32x4){0.f, 0.f, 0.f, 0.f}, s1 = (f32x4){0.f, 0.f, 0.f, 0.f};
    #pragma unroll
    for (int kk = 0; kk < 10; ++kk) {
      bf16x8 ka0 = *(const bf16x8*)&Klds[i16 * 328 + kk * 32 + g * 8];
      bf16x8 ka1 = *(const bf16x8*)&Klds[(16 + i16) * 328 + kk * 32 + g * 8];
      s0 = __builtin_amdgcn_mfma_f32_16x16x32_bf16(ka0, qf[kk], s0, 0, 0, 0);
      s1 = __builtin_amdgcn_mfma_f32_16x16x32_bf16(ka1, qf[kk], s1, 0, 0, 0);
    }
    // logits L = sim*ALPHA + bias; lane owns row i=i16, j = {4g+r} u {16+4g+r}
    f32x4 bia0 = *(const f32x4*)&biaslds[g * 4];
    f32x4 bia1 = *(const f32x4*)&biaslds[16 + g * 4];
    float L[8];
    #pragma unroll
    for (int r = 0; r < 4; ++r) { L[r] = s0[r] * ALPHA_ + bia0[r]; L[4 + r] = s1[r] * ALPHA_ + bia1[r]; }
    float tm = L[0];
    #pragma unroll
    for (int r = 1; r < 8; ++r) tm = fmaxf(tm, L[r]);
    tm = fmaxf(tm, __shfl_xor(tm, 16));
    tm = fmaxf(tm, __shfl_xor(tm, 32));
    bool upd = tm > m_run + 8.0f;                 // defer-max (T13)
    if (__any(upd)) {
      float m_new = upd ? tm : m_run;
      float fr = __expf(m_run - m_new);
      d_run *= fr;
      m_run = m_new;
      float f0 = __shfl(fr, g * 4 + 0), f1 = __shfl(fr, g * 4 + 1);
      float f2 = __shfl(fr, g * 4 + 2), f3 = __shfl(fr, g * 4 + 3);
      #pragma unroll
      for (int f = 0; f < 20; ++f) { O[f][0] *= f0; O[f][1] *= f1; O[f][2] *= f2; O[f][3] *= f3; }
    }
    float p[8], ts = 0.f;
    #pragma unroll
    for (int a = 0; a < 8; ++a) { p[a] = __expf(L[a] - m_run); ts += p[a]; }
    ts += __shfl_xor(ts, 16);
    ts += __shfl_xor(ts, 32);
    d_run += ts;
    // redistribute P (S^T C-layout) -> PV A-fragment layout (lane: row i16, j = 8g..8g+7)
    u32 u0 = pack2(p[0], p[1]), u1 = pack2(p[2], p[3]), u2 = pack2(p[4], p[5]), u3 = pack2(p[6], p[7]);
    int srcA = ((g & 1) << 5) + i16;
    int srcB = srcA + 16;
    u32 a0 = (u32)__shfl((int)u0, srcA), a1 = (u32)__shfl((int)u1, srcA);
    u32 a2 = (u32)__shfl((int)u2, srcA), a3 = (u32)__shfl((int)u3, srcA);
    u32 b0 = (u32)__shfl((int)u0, srcB), b1 = (u32)__shfl((int)u1, srcB);
    u32 b2 = (u32)__shfl((int)u2, srcB), b3 = (u32)__shfl((int)u3, srcB);
    union { bf16x8 v; u32 u[4]; } pa;
    bool lo = (g < 2);
    pa.u[0] = lo ? a0 : a2;
    pa.u[1] = lo ? a1 : a3;
    pa.u[2] = lo ? b0 : b2;
    pa.u[3] = lo ? b1 : b3;
    // PV: O[i][c] += P[i][j] * V[j][c]
    #pragma unroll
    for (int f = 0; f < 20; ++f) {
      bf16x8 vf = *(const bf16x8*)&VTlds[(f * 16 + i16) * 40 + g * 8];
      O[f] = __builtin_amdgcn_mfma_f32_16x16x32_bf16(pa.v, vf, O[f], 0, 0, 0);
    }
  }

  // normalize + store to (b, n, r, h*64+d) layout as bf16
  float d0 = __shfl(d_run, g * 4 + 0), d1 = __shfl(d_run, g * 4 + 1);
  float d2 = __shfl(d_run, g * 4 + 2), d3 = __shfl(d_run, g * 4 + 3);
  f32x4 inv = (f32x4){1.f / d0, 1.f / d1, 1.f / d2, 1.f / d3};
  #pragma unroll
  for (int f = 0; f < 20; ++f) {
    int c = f * 16 + i16;
    int rr = c >> 6, dd = c & 63;
    #pragma unroll
    for (int reg = 0; reg < 4; ++reg) {
      int gi = i0 + g * 4 + reg;
      attout[(size_t)((b * N_ + gi) * R_ + rr) * 1024 + h * 64 + dd] = f2bf(O[f][reg] * inv[reg]);
    }
  }
}

extern "C" void kernel_launch(void* const* d_in, const int* in_sizes, int n_in,
                              void* d_out, int out_size, void* d_ws, size_t ws_size,
                              hipStream_t stream) {
  (void)in_sizes; (void)n_in; (void)out_size; (void)ws_size;
  const float* x      = (const float*)d_in[0];
  const void*  mask   = d_in[1];
  const float* g_in   = (const float*)d_in[2];
  const float* Wq     = (const float*)d_in[3];
  const float* Wkv    = (const float*)d_in[4];
  const float* nullkv = (const float*)d_in[5];
  const float* Wout   = (const float*)d_in[6];
  const float* g_out  = (const float*)d_in[7];
  float* out = (float*)d_out;

  char* base = (char*)d_ws;
  size_t off = 0;
  auto carve = [&](size_t bytes) { char* r = base + off; off += (bytes + 255) & ~(size_t)255; return r; };
  int*   flag  = (int*)carve(4);
  float* biasg = (float*)carve((size_t)B_ * NJ * 4);
  u16* WqT   = (u16*)carve((size_t)1024 * 1024 * 2);
  u16* WkvT  = (u16*)carve((size_t)128 * 1024 * 2);
  u16* WoutT = (u16*)carve((size_t)1024 * 1024 * 2);
  u16* xn    = (u16*)carve((size_t)MROWS * 1024 * 2);
  u16* xb    = (u16*)carve((size_t)MROWS * 1024 * 2);
  u16* qb    = (u16*)carve((size_t)MROWS * 1024 * 2);
  u16* kg    = (u16*)carve((size_t)B_ * NJ * CDIM * 2);
  u16* vTg   = (u16*)carve((size_t)B_ * CDIM * NJ * 2);
  u16* attout = xn;   // xn dead after q-proj; reuse region for attention output

  hipMemsetAsync(flag, 0, 4, stream);
  mask_detect<<<1, 256, 0, stream>>>((const u32*)mask, flag);
  build_bias<<<(B_ * NJ + 255) / 256, 256, 0, stream>>>(mask, flag, biasg);
  kvfill<<<(B_ * 32 * CDIM + 255) / 256, 256, 0, stream>>>(nullkv, kg, vTg);
  transpose_cast<<<dim3(32, 32), 256, 0, stream>>>(Wq, WqT, 1024, 1024);
  transpose_cast<<<dim3(4, 32), 256, 0, stream>>>(Wkv, WkvT, 1024, 128);
  transpose_cast<<<dim3(32, 32), 256, 0, stream>>>(Wout, WoutT, 1024, 1024);
  ln_in<<<MROWS, 256, 0, stream>>>(x, g_in, xn, xb);
  gemm_bt<0><<<dim3(8, 160), 256, 0, stream>>>(xn, WqT, qb, nullptr, 1024, 1024);
  gemm_bt<1><<<dim3(1, 160), 256, 0, stream>>>(xb, WkvT, kg, vTg, 1024, 128);
  attn_kernel<<<1024, 256, 0, stream>>>(qb, kg, vTg, biasg, attout);
  gemm_bt<2><<<dim3(8, 160), 256, 0, stream>>>(attout, WoutT, out, nullptr, 1024, 1024);
  ln_out<<<MROWS, 256, 0, stream>>>(out, g_out);
}